// Round 8
// baseline (133.562 us; speedup 1.0000x reference)
//
#include <hip/hip_runtime.h>
#include <hip/hip_bf16.h>

#define N_EDGES 1000000
#define N_TILES (N_EDGES / 16)
#define N_NODES 100000

typedef __attribute__((ext_vector_type(8))) short short8;
typedef __attribute__((ext_vector_type(4))) float floatx4;

__device__ __forceinline__ short f2bf(float f) {
    __bf16 b = (__bf16)f;           // RNE convert, native on gfx950
    return __builtin_bit_cast(short, b);
}

// |a-b| and a*b elementwise in bf16 (no f32 round-trip; same RNE results)
union BU { short8 s8; __hip_bfloat162 b2[4]; };
__device__ __forceinline__ void dp8(short8 a, short8 b, short8& d, short8& p) {
    BU ua, ub, ud, up;
    ua.s8 = a; ub.s8 = b;
#pragma unroll
    for (int i = 0; i < 4; ++i) {
        ud.b2[i] = __hsub2(ua.b2[i], ub.b2[i]);
        up.b2[i] = __hmul2(ua.b2[i], ub.b2[i]);
    }
#pragma unroll
    for (int j = 0; j < 8; ++j) ud.s8[j] = (short)(ud.s8[j] & 0x7fff);  // bf16 abs
    d = ud.s8; p = up.s8;
}

// ---- h fp32 -> bf16, 8 elems/thread
__global__ __launch_bounds__(256) void conv_kernel(const float* __restrict__ h,
                                                   unsigned short* __restrict__ hb) {
    const int i = blockIdx.x * blockDim.x + threadIdx.x;
    if (i >= (N_NODES * 64) / 8) return;
    const float* p = h + (long)i * 8;
    floatx4 a = *(const floatx4*)p;
    floatx4 b = *(const floatx4*)(p + 4);
    short8 o;
    o[0] = f2bf(a[0]); o[1] = f2bf(a[1]); o[2] = f2bf(a[2]); o[3] = f2bf(a[3]);
    o[4] = f2bf(b[0]); o[5] = f2bf(b[1]); o[6] = f2bf(b[2]); o[7] = f2bf(b[3]);
    *(short8*)(hb + (long)i * 8) = o;
}

// ---- W prep: one block per output n (32 blocks x 256 threads)
__global__ __launch_bounds__(256) void wprep_kernel(const float* __restrict__ gamma,
                                                    const float* __restrict__ beta,
                                                    const float* __restrict__ W1,
                                                    unsigned short* __restrict__ Wt,
                                                    float* __restrict__ GB) {
    const int n = blockIdx.x;
    const int k = threadIdx.x;
    const float w1 = W1[k * 32 + n];
    float G = gamma[k] * w1;
    float B = beta[k] * w1;
    Wt[n * 256 + k] = (unsigned short)f2bf(G);
    G += __shfl_xor(G, 1);  B += __shfl_xor(B, 1);
    G += __shfl_xor(G, 2);  B += __shfl_xor(B, 2);
    G += __shfl_xor(G, 4);  B += __shfl_xor(B, 4);
    G += __shfl_xor(G, 8);  B += __shfl_xor(B, 8);
    G += __shfl_xor(G, 16); B += __shfl_xor(B, 16);
    G += __shfl_xor(G, 32); B += __shfl_xor(B, 32);
    __shared__ float sG[4], sB[4];
    if ((k & 63) == 0) { sG[k >> 6] = G; sB[k >> 6] = B; }
    __syncthreads();
    if (k == 0) {
        GB[n]      = sG[0] + sG[1] + sG[2] + sG[3];
        GB[32 + n] = sB[0] + sB[1] + sB[2] + sB[3];
    }
}

// ---- main: R7 structure (LDS B-frags, VGPR 56) + 2-deep gather pipeline.
// R5's 2-deep failed at VGPR 84->88 (occupancy cliff); at 56->~72 there is
// headroom, so this isolates the latency-cover variable at ~constant occupancy.
__global__ __launch_bounds__(256) void edgehead_kernel(
    const unsigned short* __restrict__ hb,
    const int* __restrict__ ep,
    const float* __restrict__ b1,
    const float* __restrict__ W2,
    const float* __restrict__ b2p,
    const unsigned short* __restrict__ Wt,
    const float* __restrict__ GB,
    float* __restrict__ out)
{
    const int lane = threadIdx.x & 63;
    const int c = lane & 15;   // A-row index; D column
    const int q = lane >> 4;   // quad
    const int wid = (int)((blockIdx.x * blockDim.x + threadIdx.x) >> 6);
    const int nw = (int)((gridDim.x * blockDim.x) >> 6);

    // Stage Wt into LDS, fragment-major: row r = n (0..31), chunk j = 4s+q (0..31).
    __shared__ short lds_wt[32 * 33 * 8];   // 16,896 B
    for (int idx = threadIdx.x; idx < 1024; idx += 256) {
        const int r = idx >> 5, j = idx & 31;
        *(short8*)(lds_wt + (r * 33 + j) * 8) = *(const short8*)(Wt + r * 256 + 8 * j);
    }
    __syncthreads();

    // per-lane base offset (in shorts) for its fragments: row c / row 16+c, chunk q
    int wt_off = (c * 33 + q) * 8;          // nt=0; nt=1 adds 16*33*8
    short8 ones;
#pragma unroll
    for (int j = 0; j < 8; ++j) ones[j] = (short)0x3F80;   // bf16 1.0

    // selector B for the final dot: B[8q+j][c] = (c == 4q+(j&3)) ? 1 : 0
    short8 wsel;
#pragma unroll
    for (int j = 0; j < 8; ++j) wsel[j] = (c == 4 * q + (j & 3)) ? (short)0x3F80 : (short)0;

    const float Gn0 = GB[c],      Gn1 = GB[16 + c];
    const float Bn0 = GB[32 + c] + b1[c];
    const float Bn1 = GB[48 + c] + b1[16 + c];
    const float W20 = W2[c],      W21 = W2[16 + c];
    const float b2  = b2p[0];

    int t = wid;
    if (t >= N_TILES) return;

    // --- 2-deep prologue: rows(t), rows(t+nw) in flight; idx(t+2nw) loaded
    int si = ep[t * 16 + c];
    int di = ep[N_EDGES + t * 16 + c];
    short8 au0 = *(const short8*)(hb + (long)si * 64 + 8 * q);
    short8 au1 = *(const short8*)(hb + (long)si * 64 + 8 * q + 32);
    short8 av0 = *(const short8*)(hb + (long)di * 64 + 8 * q);
    short8 av1 = *(const short8*)(hb + (long)di * 64 + 8 * q + 32);
    {
        const int t1 = t + nw;
        const int e1 = (t1 < N_TILES ? t1 : t) * 16 + c;
        si = ep[e1];
        di = ep[N_EDGES + e1];
    }
    short8 bu0 = *(const short8*)(hb + (long)si * 64 + 8 * q);
    short8 bu1 = *(const short8*)(hb + (long)si * 64 + 8 * q + 32);
    short8 bv0 = *(const short8*)(hb + (long)di * 64 + 8 * q);
    short8 bv1 = *(const short8*)(hb + (long)di * 64 + 8 * q + 32);
    {
        const int t2 = t + 2 * nw;
        const int e2 = (t2 < N_TILES ? t2 : t) * 16 + c;
        si = ep[e2];
        di = ep[N_EDGES + e2];
    }

    for (; t < N_TILES; t += nw) {
        // defeat LICM: compiler must re-read B-fragments from LDS each iter
        asm("" : "+v"(wt_off));

        // issue rows for t+2nw (two bodies of latency cover)
        short8 cu0 = *(const short8*)(hb + (long)si * 64 + 8 * q);
        short8 cu1 = *(const short8*)(hb + (long)si * 64 + 8 * q + 32);
        short8 cv0 = *(const short8*)(hb + (long)di * 64 + 8 * q);
        short8 cv1 = *(const short8*)(hb + (long)di * 64 + 8 * q + 32);
        // prefetch idx(t+3nw)
        {
            const int tn = t + 3 * nw;
            const int en = (tn < N_TILES ? tn : t) * 16 + c;
            si = ep[en];
            di = ep[N_EDGES + en];
        }

        // feat build fully in bf16 (packed)
        short8 ad0, ad1, ap0, ap1;
        dp8(au0, av0, ad0, ap0);
        dp8(au1, av1, ad1, ap1);

        floatx4 acc0 = {0.f, 0.f, 0.f, 0.f};
        floatx4 acc1 = {0.f, 0.f, 0.f, 0.f};
        floatx4 asum = {0.f, 0.f, 0.f, 0.f};   // row sums (same in every column lane)
        floatx4 agrm = {0.f, 0.f, 0.f, 0.f};   // Gram; diagonal = sum of squares
#pragma unroll
        for (int s = 0; s < 8; ++s) {
            short8 af;
            switch (s) {
                case 0: af = au0; break;
                case 1: af = au1; break;
                case 2: af = av0; break;
                case 3: af = av1; break;
                case 4: af = ad0; break;
                case 5: af = ad1; break;
                case 6: af = ap0; break;
                default: af = ap1; break;
            }
            const short8 bf0 = *(const short8*)(lds_wt + wt_off + s * 32);
            const short8 bf1 = *(const short8*)(lds_wt + wt_off + 16 * 33 * 8 + s * 32);
            acc0 = __builtin_amdgcn_mfma_f32_16x16x32_bf16(af, bf0,  acc0, 0, 0, 0);
            acc1 = __builtin_amdgcn_mfma_f32_16x16x32_bf16(af, bf1,  acc1, 0, 0, 0);
            asum = __builtin_amdgcn_mfma_f32_16x16x32_bf16(af, ones, asum, 0, 0, 0);
            agrm = __builtin_amdgcn_mfma_f32_16x16x32_bf16(af, af,   agrm, 0, 0, 0);
        }

        // LN epilogue + hmid*W2 packed as A-fragment for the selector MFMA.
        float ss[4];
#pragma unroll
        for (int r = 0; r < 4; ++r) ss[r] = __shfl(agrm[r], 20 * q + r);
        short8 af2;
#pragma unroll
        for (int r = 0; r < 4; ++r) {
            const float mu  = asum[r] * (1.f / 256.f);
            const float var = fmaf(ss[r], 1.f / 256.f, -mu * mu);
            const float rs  = rsqrtf(var + 1e-5f);
            float h0 = fmaf(rs, fmaf(-mu, Gn0, acc0[r]), Bn0); h0 = fmaxf(h0, 0.f);
            float h1 = fmaf(rs, fmaf(-mu, Gn1, acc1[r]), Bn1); h1 = fmaxf(h1, 0.f);
            af2[r]     = f2bf(h0 * W20);
            af2[4 + r] = f2bf(h1 * W21);
        }
        floatx4 dfin = {0.f, 0.f, 0.f, 0.f};
        dfin = __builtin_amdgcn_mfma_f32_16x16x32_bf16(af2, wsel, dfin, 0, 0, 0);
        float part = (dfin[0] + dfin[1]) + (dfin[2] + dfin[3]);
        part += __shfl_xor(part, 16);
        part += __shfl_xor(part, 32);
        if (q == 0) out[t * 16 + c] = part + b2;   // coalesced 64B store

        // rotate the 2-deep pipeline
        au0 = bu0; au1 = bu1; av0 = bv0; av1 = bv1;
        bu0 = cu0; bu1 = cu1; bv0 = cv0; bv1 = cv1;
    }
}

extern "C" void kernel_launch(void* const* d_in, const int* in_sizes, int n_in,
                              void* d_out, int out_size, void* d_ws, size_t ws_size,
                              hipStream_t stream) {
    const float* h     = (const float*)d_in[0];
    const int*   ep    = (const int*)d_in[1];
    const float* gamma = (const float*)d_in[2];
    const float* beta  = (const float*)d_in[3];
    const float* W1    = (const float*)d_in[4];
    const float* b1    = (const float*)d_in[5];
    const float* W2    = (const float*)d_in[6];
    const float* b2    = (const float*)d_in[7];
    float* out = (float*)d_out;

    unsigned short* hb = (unsigned short*)d_ws;                      // 12,800,000 B
    unsigned short* Wt = (unsigned short*)((char*)d_ws + 12800000);  // 16,384 B
    float* GB = (float*)((char*)d_ws + 12800000 + 16384);            // 64 floats

    conv_kernel<<<(N_NODES * 64 / 8 + 255) / 256, 256, 0, stream>>>(h, hb);
    wprep_kernel<<<32, 256, 0, stream>>>(gamma, beta, W1, Wt, GB);
    edgehead_kernel<<<2048, 256, 0, stream>>>(hb, ep, b1, W2, b2, Wt, GB, out);
}

// Round 10
// 131.774 us; speedup vs baseline: 1.0136x; 1.0136x over previous
//
#include <hip/hip_runtime.h>
#include <hip/hip_bf16.h>

#define N_EDGES 1000000
#define N_TILES (N_EDGES / 16)
#define N_NODES 100000

typedef __attribute__((ext_vector_type(8))) short short8;
typedef __attribute__((ext_vector_type(4))) float floatx4;

__device__ __forceinline__ short f2bf(float f) {
    __bf16 b = (__bf16)f;           // RNE convert, native on gfx950
    return __builtin_bit_cast(short, b);
}

// |a-b| and a*b elementwise in bf16 (no f32 round-trip; same RNE results)
union BU { short8 s8; __hip_bfloat162 b2[4]; };
__device__ __forceinline__ void dp8(short8 a, short8 b, short8& d, short8& p) {
    BU ua, ub, ud, up;
    ua.s8 = a; ub.s8 = b;
#pragma unroll
    for (int i = 0; i < 4; ++i) {
        ud.b2[i] = __hsub2(ua.b2[i], ub.b2[i]);
        up.b2[i] = __hmul2(ua.b2[i], ub.b2[i]);
    }
#pragma unroll
    for (int j = 0; j < 8; ++j) ud.s8[j] = (short)(ud.s8[j] & 0x7fff);  // bf16 abs
    d = ud.s8; p = up.s8;
}

// ---- h fp32 -> bf16, 8 elems/thread
__global__ __launch_bounds__(256) void conv_kernel(const float* __restrict__ h,
                                                   unsigned short* __restrict__ hb) {
    const int i = blockIdx.x * blockDim.x + threadIdx.x;
    if (i >= (N_NODES * 64) / 8) return;
    const float* p = h + (long)i * 8;
    floatx4 a = *(const floatx4*)p;
    floatx4 b = *(const floatx4*)(p + 4);
    short8 o;
    o[0] = f2bf(a[0]); o[1] = f2bf(a[1]); o[2] = f2bf(a[2]); o[3] = f2bf(a[3]);
    o[4] = f2bf(b[0]); o[5] = f2bf(b[1]); o[6] = f2bf(b[2]); o[7] = f2bf(b[3]);
    *(short8*)(hb + (long)i * 8) = o;
}

// ---- W prep: one block per output n (32 blocks x 256 threads)
__global__ __launch_bounds__(256) void wprep_kernel(const float* __restrict__ gamma,
                                                    const float* __restrict__ beta,
                                                    const float* __restrict__ W1,
                                                    unsigned short* __restrict__ Wt,
                                                    float* __restrict__ GB) {
    const int n = blockIdx.x;
    const int k = threadIdx.x;
    const float w1 = W1[k * 32 + n];
    float G = gamma[k] * w1;
    float B = beta[k] * w1;
    Wt[n * 256 + k] = (unsigned short)f2bf(G);
    G += __shfl_xor(G, 1);  B += __shfl_xor(B, 1);
    G += __shfl_xor(G, 2);  B += __shfl_xor(B, 2);
    G += __shfl_xor(G, 4);  B += __shfl_xor(B, 4);
    G += __shfl_xor(G, 8);  B += __shfl_xor(B, 8);
    G += __shfl_xor(G, 16); B += __shfl_xor(B, 16);
    G += __shfl_xor(G, 32); B += __shfl_xor(B, 32);
    __shared__ float sG[4], sB[4];
    if ((k & 63) == 0) { sG[k >> 6] = G; sB[k >> 6] = B; }
    __syncthreads();
    if (k == 0) {
        GB[n]      = sG[0] + sG[1] + sG[2] + sG[3];
        GB[32 + n] = sB[0] + sB[1] + sB[2] + sB[3];
    }
}

// ---- main: R7 configuration (best known: edgehead ~52 us).
// 16 edges/wave; MFMA computes MLP, LN stats (ones-B + Gram diag), and the
// final W2 dot (selector-B). B-fragments live in LDS (fragment-major, stride
// 33 chunks) to keep unified VGPR+AGPR footprint low -> ~33% occupancy.
// Gather is the bound: FETCH ~93 MB = hb x 8 XCDs (structural), fill rate
// ~7.3 B/cyc/CU ~ 73% of streaming ceiling with a random 128 B gather.
__global__ __launch_bounds__(256) void edgehead_kernel(
    const unsigned short* __restrict__ hb,
    const int* __restrict__ ep,
    const float* __restrict__ b1,
    const float* __restrict__ W2,
    const float* __restrict__ b2p,
    const unsigned short* __restrict__ Wt,
    const float* __restrict__ GB,
    float* __restrict__ out)
{
    const int lane = threadIdx.x & 63;
    const int c = lane & 15;   // A-row index; D column
    const int q = lane >> 4;   // quad
    const int wid = (int)((blockIdx.x * blockDim.x + threadIdx.x) >> 6);
    const int nw = (int)((gridDim.x * blockDim.x) >> 6);

    // Stage Wt into LDS, fragment-major: row r = n (0..31), chunk j = 4s+q (0..31).
    __shared__ short lds_wt[32 * 33 * 8];   // 16,896 B
    for (int idx = threadIdx.x; idx < 1024; idx += 256) {
        const int r = idx >> 5, j = idx & 31;
        *(short8*)(lds_wt + (r * 33 + j) * 8) = *(const short8*)(Wt + r * 256 + 8 * j);
    }
    __syncthreads();

    // per-lane base offset (in shorts) for its fragments: row c / row 16+c, chunk q
    int wt_off = (c * 33 + q) * 8;          // nt=0; nt=1 adds 16*33*8
    short8 ones;
#pragma unroll
    for (int j = 0; j < 8; ++j) ones[j] = (short)0x3F80;   // bf16 1.0

    // selector B for the final dot: B[8q+j][c] = (c == 4q+(j&3)) ? 1 : 0
    short8 wsel;
#pragma unroll
    for (int j = 0; j < 8; ++j) wsel[j] = (c == 4 * q + (j & 3)) ? (short)0x3F80 : (short)0;

    const float Gn0 = GB[c],      Gn1 = GB[16 + c];
    const float Bn0 = GB[32 + c] + b1[c];
    const float Bn1 = GB[48 + c] + b1[16 + c];
    const float W20 = W2[c],      W21 = W2[16 + c];
    const float b2  = b2p[0];

    int t = wid;
    if (t >= N_TILES) return;

    // --- prologue: rows(t), idx(t+nw)
    int s0 = ep[t * 16 + c];
    int d0 = ep[N_EDGES + t * 16 + c];
    short8 au0 = *(const short8*)(hb + (long)s0 * 64 + 8 * q);
    short8 au1 = *(const short8*)(hb + (long)s0 * 64 + 8 * q + 32);
    short8 av0 = *(const short8*)(hb + (long)d0 * 64 + 8 * q);
    short8 av1 = *(const short8*)(hb + (long)d0 * 64 + 8 * q + 32);
    int t1 = t + nw;
    int e1 = (t1 < N_TILES ? t1 : t) * 16 + c;
    int s1i = ep[e1];
    int d1i = ep[N_EDGES + e1];

    for (; t < N_TILES; t += nw) {
        // defeat LICM: compiler must re-read B-fragments from LDS each iter
        asm("" : "+v"(wt_off));

        // issue next tile's row loads (latency overlapped with compute below)
        short8 nu0 = *(const short8*)(hb + (long)s1i * 64 + 8 * q);
        short8 nu1 = *(const short8*)(hb + (long)s1i * 64 + 8 * q + 32);
        short8 nv0 = *(const short8*)(hb + (long)d1i * 64 + 8 * q);
        short8 nv1 = *(const short8*)(hb + (long)d1i * 64 + 8 * q + 32);
        // prefetch idx(t+2nw)
        {
            const int tn = t + 2 * nw;
            const int en = (tn < N_TILES ? tn : t) * 16 + c;
            s1i = ep[en];
            d1i = ep[N_EDGES + en];
        }

        // feat build fully in bf16 (packed)
        short8 ad0, ad1, ap0, ap1;
        dp8(au0, av0, ad0, ap0);
        dp8(au1, av1, ad1, ap1);

        floatx4 acc0 = {0.f, 0.f, 0.f, 0.f};
        floatx4 acc1 = {0.f, 0.f, 0.f, 0.f};
        floatx4 asum = {0.f, 0.f, 0.f, 0.f};   // row sums (same in every column lane)
        floatx4 agrm = {0.f, 0.f, 0.f, 0.f};   // Gram; diagonal = sum of squares
#pragma unroll
        for (int s = 0; s < 8; ++s) {
            short8 af;
            switch (s) {
                case 0: af = au0; break;
                case 1: af = au1; break;
                case 2: af = av0; break;
                case 3: af = av1; break;
                case 4: af = ad0; break;
                case 5: af = ad1; break;
                case 6: af = ap0; break;
                default: af = ap1; break;
            }
            const short8 bf0 = *(const short8*)(lds_wt + wt_off + s * 32);
            const short8 bf1 = *(const short8*)(lds_wt + wt_off + 16 * 33 * 8 + s * 32);
            acc0 = __builtin_amdgcn_mfma_f32_16x16x32_bf16(af, bf0,  acc0, 0, 0, 0);
            acc1 = __builtin_amdgcn_mfma_f32_16x16x32_bf16(af, bf1,  acc1, 0, 0, 0);
            asum = __builtin_amdgcn_mfma_f32_16x16x32_bf16(af, ones, asum, 0, 0, 0);
            agrm = __builtin_amdgcn_mfma_f32_16x16x32_bf16(af, af,   agrm, 0, 0, 0);
        }

        // LN epilogue + hmid*W2 packed as A-fragment for the selector MFMA.
        // acc0[r] = pre-LN hmid[edge=4q+r][n=c]; acc1[r] = [n=16+c].
        float ss[4];
#pragma unroll
        for (int r = 0; r < 4; ++r) ss[r] = __shfl(agrm[r], 20 * q + r);
        short8 af2;
#pragma unroll
        for (int r = 0; r < 4; ++r) {
            const float mu  = asum[r] * (1.f / 256.f);
            const float var = fmaf(ss[r], 1.f / 256.f, -mu * mu);
            const float rs  = rsqrtf(var + 1e-5f);
            float h0 = fmaf(rs, fmaf(-mu, Gn0, acc0[r]), Bn0); h0 = fmaxf(h0, 0.f);
            float h1 = fmaf(rs, fmaf(-mu, Gn1, acc1[r]), Bn1); h1 = fmaxf(h1, 0.f);
            af2[r]     = f2bf(h0 * W20);
            af2[4 + r] = f2bf(h1 * W21);
        }
        floatx4 dfin = {0.f, 0.f, 0.f, 0.f};
        dfin = __builtin_amdgcn_mfma_f32_16x16x32_bf16(af2, wsel, dfin, 0, 0, 0);
        // lane (c,q) reg r = hmidW2[c][4q+r] + hmidW2[c][4q+r+16]
        float part = (dfin[0] + dfin[1]) + (dfin[2] + dfin[3]);
        part += __shfl_xor(part, 16);
        part += __shfl_xor(part, 32);
        if (q == 0) out[t * 16 + c] = part + b2;   // coalesced 64B store

        au0 = nu0; au1 = nu1; av0 = nv0; av1 = nv1;
    }
}

extern "C" void kernel_launch(void* const* d_in, const int* in_sizes, int n_in,
                              void* d_out, int out_size, void* d_ws, size_t ws_size,
                              hipStream_t stream) {
    const float* h     = (const float*)d_in[0];
    const int*   ep    = (const int*)d_in[1];
    const float* gamma = (const float*)d_in[2];
    const float* beta  = (const float*)d_in[3];
    const float* W1    = (const float*)d_in[4];
    const float* b1    = (const float*)d_in[5];
    const float* W2    = (const float*)d_in[6];
    const float* b2    = (const float*)d_in[7];
    float* out = (float*)d_out;

    unsigned short* hb = (unsigned short*)d_ws;                      // 12,800,000 B
    unsigned short* Wt = (unsigned short*)((char*)d_ws + 12800000);  // 16,384 B
    float* GB = (float*)((char*)d_ws + 12800000 + 16384);            // 64 floats

    conv_kernel<<<(N_NODES * 64 / 8 + 255) / 256, 256, 0, stream>>>(h, hb);
    wprep_kernel<<<32, 256, 0, stream>>>(gamma, beta, W1, Wt, GB);
    edgehead_kernel<<<2048, 256, 0, stream>>>(hb, ep, b1, W2, b2, Wt, GB, out);
}